// Round 7
// baseline (668.297 us; speedup 1.0000x reference)
//
#include <hip/hip_runtime.h>
#include <hip/hip_fp16.h>

// TransPITF: r = u·(σ_u(t) - σ_u(nt)) + i·(σ_i(t) - σ_i(nt))
//
//  1) prep kernel (fused): block-range split between
//     (a) tag-table precompute: D = σ_u(tag)-0.5, E = σ_i(tag)-0.5, fp16
//        interleaved C[tag] = 16 x 16B chunks {D[4c..4c+3], E[4c..4c+3]}.
//        2 tags/thread so every LDS w-read is reused twice (LDS-BW bound).
//     (b) fp16 conversion of user_vecs + hot item_vecs (all x columns are
//        drawn from [0, NUM_USER) per the reference's randint).
//  2) score: 16 lanes/row, 2 rows/thread, 8 independent gathers in flight.
//     768 B/row logical (u 128, i 128, C[t] 256, C[nt] 256) — fp16 floor.

__device__ __forceinline__ float sigmoidf_(float z) {
    return 1.0f / (1.0f + __expf(-z));
}

__device__ __forceinline__ int h2_as_int(__half2 h) {
    union { __half2 h; int i; } u; u.h = h; return u.i;
}
__device__ __forceinline__ __half2 int_as_h2(int i) {
    union { __half2 h; int i; } u; u.i = i; return u.h;
}

#define TAG_BLOCKS_T(nt)  (((nt) + 511) / 512)   // 512 tags per block (2/thread)

__global__ __launch_bounds__(256, 1) void prep_kernel(
    const float* __restrict__ tag_vecs,
    const float* __restrict__ w_user, const float* __restrict__ b_user,
    const float* __restrict__ w_item, const float* __restrict__ b_item,
    const float* __restrict__ user_vecs,
    const float* __restrict__ item_vecs,
    int4* __restrict__ C, int2* __restrict__ U16, int2* __restrict__ I16,
    int num_tag, int nu4, int ni4)
{
    const int tag_blocks = TAG_BLOCKS_T(num_tag);

    if ((int)blockIdx.x >= tag_blocks) {
        // ---- convert branch: fp32 -> fp16 streaming ----
        int cb = blockIdx.x - tag_blocks;
        int nconv_blocks = gridDim.x - tag_blocks;
        int tid = cb * 256 + threadIdx.x;
        int stride = nconv_blocks * 256;
        int total = nu4 + ni4;
        for (int i = tid; i < total; i += stride) {
            float4 v;
            int2* dst;
            if (i < nu4) { v = ((const float4*)user_vecs)[i]; dst = U16 + i; }
            else         { v = ((const float4*)item_vecs)[i - nu4]; dst = I16 + (i - nu4); }
            int2 h;
            h.x = h2_as_int(__floats2half2_rn(v.x, v.y));
            h.y = h2_as_int(__floats2half2_rn(v.z, v.w));
            *dst = h;
        }
        return;
    }

    // ---- tag-table branch ----
    __shared__ float wu[64 * 64];
    __shared__ float wi[64 * 64];
    __shared__ float bu[64];
    __shared__ float bi[64];

    for (int i = threadIdx.x; i < 1024; i += 256) {
        ((float4*)wu)[i] = ((const float4*)w_user)[i];
        ((float4*)wi)[i] = ((const float4*)w_item)[i];
    }
    if (threadIdx.x < 64) {
        bu[threadIdx.x] = b_user[threadIdx.x];
        bi[threadIdx.x] = b_item[threadIdx.x];
    }
    __syncthreads();

    int tag0 = blockIdx.x * 512 + threadIdx.x;
    int tag1 = tag0 + 256;
    bool ok0 = tag0 < num_tag;
    bool ok1 = tag1 < num_tag;
    if (!ok0) return;   // tags are dense; if tag0 valid, process, tag1 guarded

    // Two tag vectors in registers (2 x 16 float4 = 128 VGPR).
    float4 tv0[16], tv1[16];
    {
        const float4* tp0 = (const float4*)(tag_vecs + (size_t)tag0 * 64);
        const float4* tp1 = (const float4*)(tag_vecs + (size_t)(ok1 ? tag1 : tag0) * 64);
        #pragma unroll
        for (int k = 0; k < 16; ++k) { tv0[k] = tp0[k]; tv1[k] = tp1[k]; }
    }

    int4* crow0 = C + (size_t)tag0 * 16;
    int4* crow1 = C + (size_t)(ok1 ? tag1 : tag0) * 16;

    for (int c = 0; c < 16; ++c) {
        float d0[4], e0[4], d1[4], e1[4];
        #pragma unroll
        for (int jj = 0; jj < 4; ++jj) {
            int j = 4 * c + jj;
            float au0 = bu[j], ai0 = bi[j];
            float au1 = au0,  ai1 = ai0;
            const float4* wur = (const float4*)(wu + j * 64);
            const float4* wir = (const float4*)(wi + j * 64);
            #pragma unroll
            for (int k = 0; k < 16; ++k) {
                float4 a = wur[k];   // LDS broadcast, shared by both tags
                float4 b = wir[k];
                float4 t0 = tv0[k];
                float4 t1 = tv1[k];
                au0 += t0.x * a.x + t0.y * a.y + t0.z * a.z + t0.w * a.w;
                ai0 += t0.x * b.x + t0.y * b.y + t0.z * b.z + t0.w * b.w;
                au1 += t1.x * a.x + t1.y * a.y + t1.z * a.z + t1.w * a.w;
                ai1 += t1.x * b.x + t1.y * b.y + t1.z * b.z + t1.w * b.w;
            }
            d0[jj] = sigmoidf_(au0) - 0.5f;
            e0[jj] = sigmoidf_(ai0) - 0.5f;
            d1[jj] = sigmoidf_(au1) - 0.5f;
            e1[jj] = sigmoidf_(ai1) - 0.5f;
        }
        int4 p0, p1;
        p0.x = h2_as_int(__floats2half2_rn(d0[0], d0[1]));
        p0.y = h2_as_int(__floats2half2_rn(d0[2], d0[3]));
        p0.z = h2_as_int(__floats2half2_rn(e0[0], e0[1]));
        p0.w = h2_as_int(__floats2half2_rn(e0[2], e0[3]));
        crow0[c] = p0;
        if (ok1) {
            p1.x = h2_as_int(__floats2half2_rn(d1[0], d1[1]));
            p1.y = h2_as_int(__floats2half2_rn(d1[2], d1[3]));
            p1.z = h2_as_int(__floats2half2_rn(e1[0], e1[1]));
            p1.w = h2_as_int(__floats2half2_rn(e1[2], e1[3]));
            crow1[c] = p1;
        }
    }
}

// 16 lanes per row, 2 rows per thread -> 8 independent gathers in flight.
__global__ __launch_bounds__(256) void score_kernel(
    const int* __restrict__ x,
    const int2* __restrict__ U16,
    const int2* __restrict__ I16,
    const float* __restrict__ item_vecs,   // fp32 fallback for ids >= n_hot
    const int4* __restrict__ C,
    float* __restrict__ out, int B, int n_hot)
{
    int sub = threadIdx.x & 15;
    int grp0 = (blockIdx.x * 256 + threadIdx.x) >> 4;
    int gstride = (gridDim.x * 256) >> 4;

    for (int grp = grp0; grp * 2 < B; grp += gstride) {
        int rowA = grp * 2;
        int rowB = rowA + 1;
        bool hasB = rowB < B;

        int4 ia = ((const int4*)x)[rowA];
        int4 ib = ((const int4*)x)[hasB ? rowB : rowA];

        // Issue all 8 gathers before consuming.
        int2 uhA = U16[(size_t)ia.x * 16 + sub];
        int4 ctA = C[(size_t)ia.z * 16 + sub];
        int4 cnA = C[(size_t)ia.w * 16 + sub];
        int2 uhB = U16[(size_t)ib.x * 16 + sub];
        int4 ctB = C[(size_t)ib.z * 16 + sub];
        int4 cnB = C[(size_t)ib.w * 16 + sub];

        float2 iA01, iA23, iB01, iB23;
        if (ia.y < n_hot) {
            int2 ih = I16[(size_t)ia.y * 16 + sub];
            iA01 = __half22float2(int_as_h2(ih.x));
            iA23 = __half22float2(int_as_h2(ih.y));
        } else {
            float4 f = ((const float4*)(item_vecs + (size_t)ia.y * 64))[sub];
            iA01 = make_float2(f.x, f.y); iA23 = make_float2(f.z, f.w);
        }
        if (ib.y < n_hot) {
            int2 ih = I16[(size_t)ib.y * 16 + sub];
            iB01 = __half22float2(int_as_h2(ih.x));
            iB23 = __half22float2(int_as_h2(ih.y));
        } else {
            float4 f = ((const float4*)(item_vecs + (size_t)ib.y * 64))[sub];
            iB01 = make_float2(f.x, f.y); iB23 = make_float2(f.z, f.w);
        }

        // Row A
        {
            float2 u01 = __half22float2(int_as_h2(uhA.x));
            float2 u23 = __half22float2(int_as_h2(uhA.y));
            float2 dt01 = __half22float2(int_as_h2(ctA.x));
            float2 dt23 = __half22float2(int_as_h2(ctA.y));
            float2 et01 = __half22float2(int_as_h2(ctA.z));
            float2 et23 = __half22float2(int_as_h2(ctA.w));
            float2 dn01 = __half22float2(int_as_h2(cnA.x));
            float2 dn23 = __half22float2(int_as_h2(cnA.y));
            float2 en01 = __half22float2(int_as_h2(cnA.z));
            float2 en23 = __half22float2(int_as_h2(cnA.w));

            float p = u01.x * (dt01.x - dn01.x) + u01.y * (dt01.y - dn01.y)
                    + u23.x * (dt23.x - dn23.x) + u23.y * (dt23.y - dn23.y)
                    + iA01.x * (et01.x - en01.x) + iA01.y * (et01.y - en01.y)
                    + iA23.x * (et23.x - en23.x) + iA23.y * (et23.y - en23.y);

            p += __shfl_xor(p, 1);
            p += __shfl_xor(p, 2);
            p += __shfl_xor(p, 4);
            p += __shfl_xor(p, 8);
            if (sub == 0) __builtin_nontemporal_store(p, out + rowA);
        }
        // Row B
        if (hasB) {
            float2 u01 = __half22float2(int_as_h2(uhB.x));
            float2 u23 = __half22float2(int_as_h2(uhB.y));
            float2 dt01 = __half22float2(int_as_h2(ctB.x));
            float2 dt23 = __half22float2(int_as_h2(ctB.y));
            float2 et01 = __half22float2(int_as_h2(ctB.z));
            float2 et23 = __half22float2(int_as_h2(ctB.w));
            float2 dn01 = __half22float2(int_as_h2(cnB.x));
            float2 dn23 = __half22float2(int_as_h2(cnB.y));
            float2 en01 = __half22float2(int_as_h2(cnB.z));
            float2 en23 = __half22float2(int_as_h2(cnB.w));

            float p = u01.x * (dt01.x - dn01.x) + u01.y * (dt01.y - dn01.y)
                    + u23.x * (dt23.x - dn23.x) + u23.y * (dt23.y - dn23.y)
                    + iB01.x * (et01.x - en01.x) + iB01.y * (et01.y - en01.y)
                    + iB23.x * (et23.x - en23.x) + iB23.y * (et23.y - en23.y);

            p += __shfl_xor(p, 1);
            p += __shfl_xor(p, 2);
            p += __shfl_xor(p, 4);
            p += __shfl_xor(p, 8);
            if (sub == 0) __builtin_nontemporal_store(p, out + rowB);
        }
    }
}

// Fallback if workspace is too small: fused, one wave per row.
__global__ __launch_bounds__(256) void fused_fallback(
    const int* __restrict__ x,
    const float* __restrict__ user_vecs,
    const float* __restrict__ item_vecs,
    const float* __restrict__ tag_vecs,
    const float* __restrict__ w_user, const float* __restrict__ b_user,
    const float* __restrict__ w_item, const float* __restrict__ b_item,
    float* __restrict__ out, int B)
{
    int tid = blockIdx.x * 256 + threadIdx.x;
    int row = tid >> 6;
    int lane = tid & 63;
    if (row >= B) return;

    int4 idx = ((const int4*)x)[row];

    float t  = tag_vecs[(size_t)idx.z * 64 + lane];
    float nt = tag_vecs[(size_t)idx.w * 64 + lane];

    const float* wur = w_user + lane * 64;
    const float* wir = w_item + lane * 64;

    float zu = b_user[lane], zi = b_item[lane];
    float nzu = zu, nzi = zi;
    #pragma unroll 8
    for (int k = 0; k < 64; ++k) {
        float tk  = __shfl(t, k, 64);
        float ntk = __shfl(nt, k, 64);
        float wuk = wur[k];
        float wik = wir[k];
        zu  += tk * wuk;  zi  += tk * wik;
        nzu += ntk * wuk; nzi += ntk * wik;
    }

    float ut  = sigmoidf_(zu);
    float itg = sigmoidf_(zi);
    float nut = sigmoidf_(nzu);
    float nit = sigmoidf_(nzi);

    float uv  = user_vecs[(size_t)idx.x * 64 + lane];
    float ivv = item_vecs[(size_t)idx.y * 64 + lane];
    float p = uv * (ut - nut) + ivv * (itg - nit);

    #pragma unroll
    for (int off = 32; off; off >>= 1) p += __shfl_xor(p, off, 64);

    if (lane == 0) out[row] = p;
}

extern "C" void kernel_launch(void* const* d_in, const int* in_sizes, int n_in,
                              void* d_out, int out_size, void* d_ws, size_t ws_size,
                              hipStream_t stream) {
    const int*   x         = (const int*)d_in[0];
    const float* user_vecs = (const float*)d_in[1];
    const float* item_vecs = (const float*)d_in[2];
    const float* tag_vecs  = (const float*)d_in[3];
    const float* w_user    = (const float*)d_in[4];
    const float* b_user    = (const float*)d_in[5];
    const float* w_item    = (const float*)d_in[6];
    const float* b_item    = (const float*)d_in[7];
    float* out = (float*)d_out;

    const int B        = in_sizes[0] / 4;
    const int num_user = in_sizes[1] / 64;
    const int num_item = in_sizes[2] / 64;
    const int num_tag  = in_sizes[3] / 64;
    const int n_hot    = (num_item < num_user) ? num_item : num_user;

    const size_t bytes_C = (size_t)num_tag * 256;
    const size_t bytes_U = (size_t)num_user * 128;
    const size_t bytes_I = (size_t)n_hot * 128;
    const size_t need = bytes_C + bytes_U + bytes_I;

    if (ws_size >= need) {
        int4* C   = (int4*)d_ws;
        int2* U16 = (int2*)((char*)d_ws + bytes_C);
        int2* I16 = (int2*)((char*)d_ws + bytes_C + bytes_U);

        int nu4 = num_user * 16;
        int ni4 = n_hot * 16;
        int tag_blocks = TAG_BLOCKS_T(num_tag);
        int conv_blocks = (nu4 + ni4 + 255) / 256;
        if (conv_blocks > 1024) conv_blocks = 1024;

        prep_kernel<<<tag_blocks + conv_blocks, 256, 0, stream>>>(
            tag_vecs, w_user, b_user, w_item, b_item,
            user_vecs, item_vecs, C, U16, I16, num_tag, nu4, ni4);

        int ngrp = (B + 1) / 2;
        int nblocks = (ngrp * 16 + 255) / 256;
        if (nblocks > 32768) nblocks = 32768;
        score_kernel<<<nblocks, 256, 0, stream>>>(
            x, U16, I16, item_vecs, C, out, B, n_hot);
    } else {
        fused_fallback<<<((size_t)B * 64 + 255) / 256, 256, 0, stream>>>(
            x, user_vecs, item_vecs, tag_vecs,
            w_user, b_user, w_item, b_item, out, B);
    }
}

// Round 8
// 508.501 us; speedup vs baseline: 1.3143x; 1.3143x over previous
//
#include <hip/hip_runtime.h>
#include <hip/hip_fp16.h>

// TransPITF: r = u·(σ_u(t) - σ_u(nt)) + i·(σ_i(t) - σ_i(nt))
//
//  1) precompute_tags: D = σ_u(tag)-0.5, E = σ_i(tag)-0.5 for all tags, fp16
//     interleaved C[tag] = 16 x 16B chunks {D[4c..4c+3], E[4c..4c+3]}.
//     1 tag/thread (2-tag blocking ballooned to 256 VGPR / 10% occupancy -> 6x slower).
//  2) convert_fp16: user_vecs + hot item_vecs (all x columns drawn from
//     [0, NUM_USER) per the reference's randint) to fp16, 128 B/row.
//  3) score: 16 lanes per 2 rows, 8 independent gathers in flight.
//     768 B/row logical (u 128, i 128, C[t] 256, C[nt] 256) — fp16 floor.

__device__ __forceinline__ float sigmoidf_(float z) {
    return 1.0f / (1.0f + __expf(-z));
}

__device__ __forceinline__ int h2_as_int(__half2 h) {
    union { __half2 h; int i; } u; u.h = h; return u.i;
}
__device__ __forceinline__ __half2 int_as_h2(int i) {
    union { __half2 h; int i; } u; u.i = i; return u.h;
}

// One thread per tag row. W_user / W_item staged in LDS (32.5 KB), broadcast reads.
__global__ __launch_bounds__(256) void precompute_tags(
    const float* __restrict__ tag_vecs,
    const float* __restrict__ w_user, const float* __restrict__ b_user,
    const float* __restrict__ w_item, const float* __restrict__ b_item,
    int4* __restrict__ C, int num_tag)
{
    __shared__ float wu[64 * 64];
    __shared__ float wi[64 * 64];
    __shared__ float bu[64];
    __shared__ float bi[64];

    for (int i = threadIdx.x; i < 1024; i += 256) {
        ((float4*)wu)[i] = ((const float4*)w_user)[i];
        ((float4*)wi)[i] = ((const float4*)w_item)[i];
    }
    if (threadIdx.x < 64) {
        bu[threadIdx.x] = b_user[threadIdx.x];
        bi[threadIdx.x] = b_item[threadIdx.x];
    }
    __syncthreads();

    int tag = blockIdx.x * 256 + threadIdx.x;
    if (tag >= num_tag) return;

    float4 tv[16];
    const float4* tp = (const float4*)(tag_vecs + (size_t)tag * 64);
    #pragma unroll
    for (int k = 0; k < 16; ++k) tv[k] = tp[k];

    int4* crow = C + (size_t)tag * 16;

    #pragma unroll 2
    for (int c = 0; c < 16; ++c) {
        float d0, d1, d2, d3, e0, e1, e2, e3;
        float* dd[4] = {&d0, &d1, &d2, &d3};
        float* ee[4] = {&e0, &e1, &e2, &e3};
        #pragma unroll
        for (int jj = 0; jj < 4; ++jj) {
            int j = 4 * c + jj;
            float au = bu[j];
            float ai = bi[j];
            const float4* wur = (const float4*)(wu + j * 64);
            const float4* wir = (const float4*)(wi + j * 64);
            #pragma unroll
            for (int k = 0; k < 16; ++k) {
                float4 a = wur[k];     // LDS broadcast
                float4 b = wir[k];
                float4 t = tv[k];
                au += t.x * a.x + t.y * a.y + t.z * a.z + t.w * a.w;
                ai += t.x * b.x + t.y * b.y + t.z * b.z + t.w * b.w;
            }
            *dd[jj] = sigmoidf_(au) - 0.5f;
            *ee[jj] = sigmoidf_(ai) - 0.5f;
        }
        int4 pack;
        pack.x = h2_as_int(__floats2half2_rn(d0, d1));
        pack.y = h2_as_int(__floats2half2_rn(d2, d3));
        pack.z = h2_as_int(__floats2half2_rn(e0, e1));
        pack.w = h2_as_int(__floats2half2_rn(e2, e3));
        crow[c] = pack;
    }
}

// fp32 -> fp16 conversion of user_vecs and item_vecs[0:n_hot] into U16 / I16.
__global__ __launch_bounds__(256) void convert_fp16(
    const float* __restrict__ user_vecs,
    const float* __restrict__ item_vecs,
    int2* __restrict__ U16, int2* __restrict__ I16,
    int nu4, int ni4)   // counts of float4 chunks
{
    int tid = blockIdx.x * 256 + threadIdx.x;
    int stride = gridDim.x * 256;
    int total = nu4 + ni4;
    for (int i = tid; i < total; i += stride) {
        float4 v;
        int2* dst;
        if (i < nu4) { v = ((const float4*)user_vecs)[i]; dst = U16 + i; }
        else         { v = ((const float4*)item_vecs)[i - nu4]; dst = I16 + (i - nu4); }
        int2 h;
        h.x = h2_as_int(__floats2half2_rn(v.x, v.y));
        h.y = h2_as_int(__floats2half2_rn(v.z, v.w));
        *dst = h;
    }
}

// 16 lanes per row, 2 rows per thread -> 8 independent gathers in flight.
__global__ __launch_bounds__(256) void score_kernel(
    const int* __restrict__ x,
    const int2* __restrict__ U16,
    const int2* __restrict__ I16,
    const float* __restrict__ item_vecs,   // fp32 fallback for ids >= n_hot
    const int4* __restrict__ C,
    float* __restrict__ out, int B, int n_hot)
{
    int sub = threadIdx.x & 15;
    int grp0 = (blockIdx.x * 256 + threadIdx.x) >> 4;
    int gstride = (gridDim.x * 256) >> 4;

    for (int grp = grp0; grp * 2 < B; grp += gstride) {
        int rowA = grp * 2;
        int rowB = rowA + 1;
        bool hasB = rowB < B;

        int4 ia = ((const int4*)x)[rowA];
        int4 ib = ((const int4*)x)[hasB ? rowB : rowA];

        // Issue all gathers before consuming.
        int2 uhA = U16[(size_t)ia.x * 16 + sub];
        int4 ctA = C[(size_t)ia.z * 16 + sub];
        int4 cnA = C[(size_t)ia.w * 16 + sub];
        int2 uhB = U16[(size_t)ib.x * 16 + sub];
        int4 ctB = C[(size_t)ib.z * 16 + sub];
        int4 cnB = C[(size_t)ib.w * 16 + sub];

        float2 iA01, iA23, iB01, iB23;
        if (ia.y < n_hot) {
            int2 ih = I16[(size_t)ia.y * 16 + sub];
            iA01 = __half22float2(int_as_h2(ih.x));
            iA23 = __half22float2(int_as_h2(ih.y));
        } else {
            float4 f = ((const float4*)(item_vecs + (size_t)ia.y * 64))[sub];
            iA01 = make_float2(f.x, f.y); iA23 = make_float2(f.z, f.w);
        }
        if (ib.y < n_hot) {
            int2 ih = I16[(size_t)ib.y * 16 + sub];
            iB01 = __half22float2(int_as_h2(ih.x));
            iB23 = __half22float2(int_as_h2(ih.y));
        } else {
            float4 f = ((const float4*)(item_vecs + (size_t)ib.y * 64))[sub];
            iB01 = make_float2(f.x, f.y); iB23 = make_float2(f.z, f.w);
        }

        // Row A
        {
            float2 u01 = __half22float2(int_as_h2(uhA.x));
            float2 u23 = __half22float2(int_as_h2(uhA.y));
            float2 dt01 = __half22float2(int_as_h2(ctA.x));
            float2 dt23 = __half22float2(int_as_h2(ctA.y));
            float2 et01 = __half22float2(int_as_h2(ctA.z));
            float2 et23 = __half22float2(int_as_h2(ctA.w));
            float2 dn01 = __half22float2(int_as_h2(cnA.x));
            float2 dn23 = __half22float2(int_as_h2(cnA.y));
            float2 en01 = __half22float2(int_as_h2(cnA.z));
            float2 en23 = __half22float2(int_as_h2(cnA.w));

            float p = u01.x * (dt01.x - dn01.x) + u01.y * (dt01.y - dn01.y)
                    + u23.x * (dt23.x - dn23.x) + u23.y * (dt23.y - dn23.y)
                    + iA01.x * (et01.x - en01.x) + iA01.y * (et01.y - en01.y)
                    + iA23.x * (et23.x - en23.x) + iA23.y * (et23.y - en23.y);

            p += __shfl_xor(p, 1);
            p += __shfl_xor(p, 2);
            p += __shfl_xor(p, 4);
            p += __shfl_xor(p, 8);
            if (sub == 0) __builtin_nontemporal_store(p, out + rowA);
        }
        // Row B
        if (hasB) {
            float2 u01 = __half22float2(int_as_h2(uhB.x));
            float2 u23 = __half22float2(int_as_h2(uhB.y));
            float2 dt01 = __half22float2(int_as_h2(ctB.x));
            float2 dt23 = __half22float2(int_as_h2(ctB.y));
            float2 et01 = __half22float2(int_as_h2(ctB.z));
            float2 et23 = __half22float2(int_as_h2(ctB.w));
            float2 dn01 = __half22float2(int_as_h2(cnB.x));
            float2 dn23 = __half22float2(int_as_h2(cnB.y));
            float2 en01 = __half22float2(int_as_h2(cnB.z));
            float2 en23 = __half22float2(int_as_h2(cnB.w));

            float p = u01.x * (dt01.x - dn01.x) + u01.y * (dt01.y - dn01.y)
                    + u23.x * (dt23.x - dn23.x) + u23.y * (dt23.y - dn23.y)
                    + iB01.x * (et01.x - en01.x) + iB01.y * (et01.y - en01.y)
                    + iB23.x * (et23.x - en23.x) + iB23.y * (et23.y - en23.y);

            p += __shfl_xor(p, 1);
            p += __shfl_xor(p, 2);
            p += __shfl_xor(p, 4);
            p += __shfl_xor(p, 8);
            if (sub == 0) __builtin_nontemporal_store(p, out + rowB);
        }
    }
}

// Fallback if workspace is too small: fused, one wave per row.
__global__ __launch_bounds__(256) void fused_fallback(
    const int* __restrict__ x,
    const float* __restrict__ user_vecs,
    const float* __restrict__ item_vecs,
    const float* __restrict__ tag_vecs,
    const float* __restrict__ w_user, const float* __restrict__ b_user,
    const float* __restrict__ w_item, const float* __restrict__ b_item,
    float* __restrict__ out, int B)
{
    int tid = blockIdx.x * 256 + threadIdx.x;
    int row = tid >> 6;
    int lane = tid & 63;
    if (row >= B) return;

    int4 idx = ((const int4*)x)[row];

    float t  = tag_vecs[(size_t)idx.z * 64 + lane];
    float nt = tag_vecs[(size_t)idx.w * 64 + lane];

    const float* wur = w_user + lane * 64;
    const float* wir = w_item + lane * 64;

    float zu = b_user[lane], zi = b_item[lane];
    float nzu = zu, nzi = zi;
    #pragma unroll 8
    for (int k = 0; k < 64; ++k) {
        float tk  = __shfl(t, k, 64);
        float ntk = __shfl(nt, k, 64);
        float wuk = wur[k];
        float wik = wir[k];
        zu  += tk * wuk;  zi  += tk * wik;
        nzu += ntk * wuk; nzi += ntk * wik;
    }

    float ut  = sigmoidf_(zu);
    float itg = sigmoidf_(zi);
    float nut = sigmoidf_(nzu);
    float nit = sigmoidf_(nzi);

    float uv  = user_vecs[(size_t)idx.x * 64 + lane];
    float ivv = item_vecs[(size_t)idx.y * 64 + lane];
    float p = uv * (ut - nut) + ivv * (itg - nit);

    #pragma unroll
    for (int off = 32; off; off >>= 1) p += __shfl_xor(p, off, 64);

    if (lane == 0) out[row] = p;
}

extern "C" void kernel_launch(void* const* d_in, const int* in_sizes, int n_in,
                              void* d_out, int out_size, void* d_ws, size_t ws_size,
                              hipStream_t stream) {
    const int*   x         = (const int*)d_in[0];
    const float* user_vecs = (const float*)d_in[1];
    const float* item_vecs = (const float*)d_in[2];
    const float* tag_vecs  = (const float*)d_in[3];
    const float* w_user    = (const float*)d_in[4];
    const float* b_user    = (const float*)d_in[5];
    const float* w_item    = (const float*)d_in[6];
    const float* b_item    = (const float*)d_in[7];
    float* out = (float*)d_out;

    const int B        = in_sizes[0] / 4;
    const int num_user = in_sizes[1] / 64;
    const int num_item = in_sizes[2] / 64;
    const int num_tag  = in_sizes[3] / 64;
    const int n_hot    = (num_item < num_user) ? num_item : num_user;

    const size_t bytes_C = (size_t)num_tag * 256;
    const size_t bytes_U = (size_t)num_user * 128;
    const size_t bytes_I = (size_t)n_hot * 128;
    const size_t need = bytes_C + bytes_U + bytes_I;

    if (ws_size >= need) {
        int4* C   = (int4*)d_ws;
        int2* U16 = (int2*)((char*)d_ws + bytes_C);
        int2* I16 = (int2*)((char*)d_ws + bytes_C + bytes_U);

        precompute_tags<<<(num_tag + 255) / 256, 256, 0, stream>>>(
            tag_vecs, w_user, b_user, w_item, b_item, C, num_tag);

        int nu4 = num_user * 16;
        int ni4 = n_hot * 16;
        int cblocks = (nu4 + ni4 + 255) / 256;
        if (cblocks > 2048) cblocks = 2048;
        convert_fp16<<<cblocks, 256, 0, stream>>>(
            user_vecs, item_vecs, U16, I16, nu4, ni4);

        int ngrp = (B + 1) / 2;
        int nblocks = (ngrp * 16 + 255) / 256;
        if (nblocks > 32768) nblocks = 32768;
        score_kernel<<<nblocks, 256, 0, stream>>>(
            x, U16, I16, item_vecs, C, out, B, n_hot);
    } else {
        fused_fallback<<<((size_t)B * 64 + 255) / 256, 256, 0, stream>>>(
            x, user_vecs, item_vecs, tag_vecs,
            w_user, b_user, w_item, b_item, out, B);
    }
}